// Round 10
// baseline (419.102 us; speedup 1.0000x reference)
//
#include <hip/hip_runtime.h>
#include <math.h>

#define T_LEN   1024
#define D_DIM   512
#define B_DIM   16
#define OUT_T   1280
#define K_SEL   16
#define TSEL    17        /* candidate rank target: 16 + 1 safety */
#define MAXC    64
#define NSPB    8         /* series per block in k_dft_topk */

// d_ws layout: [0, 2MiB) float4 sel[8192][16]  (k, re*2/N, im*2/N, 0)
// Two kernels total; all twiddles computed on the fly (no table kernel,
// no transpose kernel, d_out never used as scratch).

// ------- kernel 1: direct-staged fp32 CT DFT + 2-level histogram cut +
//         conditional fp64 refine.  One block = 8 series (b, d0..d0+7). -------
__global__ __launch_bounds__(256, 2) void k_dft_topk(const float* __restrict__ x,
                                                     float4* __restrict__ sel) {
    int blk  = blockIdx.x;           // 1024 blocks = b(16) * dtile(64)
    int b    = blk >> 6;
    int d0   = (blk & 63) * NSPB;
    int tid  = threadIdx.x;
    int lane = tid & 63;
    int w    = tid >> 6;             // wave id 0..3

    __shared__ float   xs2[NSPB][1032];           // 33 KB (pad 1032: 2-way stores)
    __shared__ __align__(16) char smemA[8448];    // zs (phase A/B) -> fineh (select)
    __shared__ float2  w32s[32];                  // e^{-2pi i m/32}
    __shared__ int     hist[512];                 // coarse histogram
    __shared__ int     candk[MAXC];
    __shared__ float2  candv[MAXC];               // fp32 (cr,ci) at gather
    __shared__ double2 candc[MAXC];               // fp64 refined (rare path)
    __shared__ int     Bsh, abovesh, fcsh, ncnt, needref;

    float2* zs    = (float2*)smemA;   // [32][33] z[k1][t0] padded
    int*    fineh = (int*)smemA;      // [1024]   fine histogram (after phase B)

    // ---- stage 8 series: x[b, t, d0+dd] -> xs2[dd][t] (float4, line-covered) ----
    const float* xb = x + ((size_t)b << 19) + d0;
#pragma unroll
    for (int i = 0; i < 8; i++) {
        int idx4 = tid + 256 * i;    // 0..2047
        int t = idx4 >> 1, q = idx4 & 1;
        float4 v = *(const float4*)(xb + ((size_t)t << 9) + 4 * q);
        xs2[4 * q + 0][t] = v.x; xs2[4 * q + 1][t] = v.y;
        xs2[4 * q + 2][t] = v.z; xs2[4 * q + 3][t] = v.w;
    }
    if (tid < 32) {                  // w32s[m] = e^{-2pi i m/32}
        float a = (-6.2831853071795864769e0f / 32.0f) * (float)tid;
        w32s[tid] = make_float2(__cosf(a), __sinf(a));
    }
    if (tid == 0) ncnt = 0;
    hist[tid] = 0; hist[tid + 256] = 0;
    __syncthreads();

    const float TH = -6.2831853071795864769e0f / 1024.0f;   // -2pi/1024

    for (int ser = 0; ser < NSPB; ser++) {
        const float* xs = xs2[ser];

        // ---- phase A: y[k1][t0] = sum_t1 x[32 t1+t0] W32^{k1 t1}; z = y*W1024^{k1 t0}
        {
            int k1  = tid & 31;
            int t0b = (tid >> 5) << 2;
            float yr0=0,yi0=0,yr1=0,yi1=0,yr2=0,yi2=0,yr3=0,yi3=0;
#pragma unroll
            for (int t1 = 0; t1 < 32; t1++) {
                const float4 xq = *(const float4*)&xs[32 * t1 + t0b];
                float2 wv = w32s[(k1 * t1) & 31];
                yr0 += xq.x * wv.x; yi0 += xq.x * wv.y;
                yr1 += xq.y * wv.x; yi1 += xq.y * wv.y;
                yr2 += xq.z * wv.x; yi2 += xq.z * wv.y;
                yr3 += xq.w * wv.x; yi3 += xq.w * wv.y;
            }
            float yrA[4] = {yr0, yr1, yr2, yr3};
            float yiA[4] = {yi0, yi1, yi2, yi3};
#pragma unroll
            for (int i = 0; i < 4; i++) {
                int t0 = t0b + i;
                int m  = (k1 * t0) & (T_LEN - 1);
                float a = TH * (float)m;           // tw = (cos, -sin) = (cn, sn)
                float sn = __sinf(a), cn = __cosf(a);
                zs[k1 * 33 + t0] = make_float2(yrA[i] * cn - yiA[i] * sn,
                                               yrA[i] * sn + yiA[i] * cn);
            }
        }
        __syncthreads();

        // ---- phase B (merged k/k+256: same zs row): c_k = sum_t0 z W32^{k0 t0}
        float crr[2], cii[2];
        int   bb[2],  ff[2];
        {
            int kb1 = tid & 31;
            int k0a = tid >> 5;
            float cr0=0, ci0=0, cr1=0, ci1=0;
#pragma unroll
            for (int t0 = 0; t0 < 32; t0++) {
                float2 z  = zs[kb1 * 33 + t0];
                float2 wa = w32s[(k0a * t0) & 31];
                float2 wb = w32s[((k0a + 8) * t0) & 31];
                cr0 += z.x * wa.x - z.y * wa.y;
                ci0 += z.x * wa.y + z.y * wa.x;
                cr1 += z.x * wb.x - z.y * wb.y;
                ci1 += z.x * wb.y + z.y * wb.x;
            }
            crr[0] = cr0; cii[0] = ci0; crr[1] = cr1; cii[1] = ci1;
        }
#pragma unroll
        for (int kk = 0; kk < 2; kk++) {
            int k = tid + kk * 256;
            if (k == 0) { bb[kk] = -1; ff[kk] = 0; }
            else {
                float mag = crr[kk] * crr[kk] + cii[kk] * cii[kk];
                unsigned int bits = __float_as_uint(mag);
                bb[kk] = (int)(bits >> 22);            // monotone coarse bucket
                ff[kk] = (int)((bits >> 12) & 1023);   // monotone within coarse
                atomicAdd(&hist[bb[kk]], 1);
            }
        }
        __syncthreads();   // S1: hist done; zs dead -> fineh

        // ---- zero fine histogram (overlays zs) ----
#pragma unroll
        for (int i = 0; i < 4; i++) fineh[tid + 256 * i] = 0;

        // ---- wave 0: coarse suffix-scan; B = largest bucket with suffix >= TSEL
        if (tid < 64) {
            int c8[8]; int ssum = 0;
            int top = 511 - lane * 8;
#pragma unroll
            for (int j = 0; j < 8; j++) { c8[j] = hist[top - j]; ssum += c8[j]; }
            int inc = ssum;
#pragma unroll
            for (int off = 1; off < 64; off <<= 1) {
                int o = __shfl_up(inc, off);
                if (lane >= off) inc += o;
            }
            int P = inc - ssum;
            if (P < TSEL && P + ssum >= TSEL) {     // exactly one lane
                int run = P;
#pragma unroll
                for (int j = 0; j < 8; j++) {
                    run += c8[j];
                    if (run >= TSEL) { Bsh = top - j; abovesh = run - c8[j]; break; }
                }
            }
        }
        __syncthreads();   // S2

        // ---- fine histogram over bins in bucket B ----
        int Bcut = Bsh;
        if (bb[0] == Bcut) atomicAdd(&fineh[ff[0]], 1);
        if (bb[1] == Bcut) atomicAdd(&fineh[ff[1]], 1);
        __syncthreads();   // S3

        // ---- wave 0: fine suffix-scan; sub-cut; -1 sub-bucket margin ----
        if (tid < 64) {
            int f16[16]; int ssum = 0;
            int ftop = 1023 - lane * 16;
#pragma unroll
            for (int j = 0; j < 16; j++) { f16[j] = fineh[ftop - j]; ssum += f16[j]; }
            int inc = ssum;
#pragma unroll
            for (int off = 1; off < 64; off <<= 1) {
                int o = __shfl_up(inc, off);
                if (lane >= off) inc += o;
            }
            int P   = inc - ssum;
            int tgt = TSEL - abovesh;    // >= 1
            if (P < tgt && P + ssum >= tgt) {       // exactly one lane
                int run = P;
#pragma unroll
                for (int j = 0; j < 16; j++) {
                    run += f16[j];
                    if (run >= tgt) {
                        int fc = ftop - j;
                        fcsh = fc > 0 ? fc - 1 : 0;
                        break;
                    }
                }
            }
        }
        __syncthreads();   // S4

        // ---- gather candidates with values ----
        int fcm = fcsh;
        if (bb[0] > Bcut || (bb[0] == Bcut && ff[0] >= fcm)) {
            int sl = atomicAdd(&ncnt, 1);
            if (sl < MAXC) { candk[sl] = tid; candv[sl] = make_float2(crr[0], cii[0]); }
        }
        if (bb[1] > Bcut || (bb[1] == Bcut && ff[1] >= fcm)) {
            int sl = atomicAdd(&ncnt, 1);
            if (sl < MAXC) { candk[sl] = tid + 256; candv[sl] = make_float2(crr[1], cii[1]); }
        }
        __syncthreads();   // S5
        int M = ncnt < MAXC ? ncnt : MAXC;

        // ---- wave 0: fp32 rank-count + boundary-gap test ----
        int    rank32 = 64;
        float  myMag  = -1.f; int myK = 1 << 20; float2 myV = make_float2(0.f, 0.f);
        if (tid < 64) {
            bool act = lane < M;
            if (act) {
                myK = candk[lane]; myV = candv[lane];
                myMag = myV.x * myV.x + myV.y * myV.y;
            }
            rank32 = 0;
            for (int j = 0; j < M; j++) {
                float om = __shfl(myMag, j);
                int   ok = __shfl(myK, j);
                rank32 += (om > myMag || (om == myMag && ok < myK)) ? 1 : 0;
            }
            float a2 = (act && rank32 == 15) ? myMag : -1.f;
            float b2 = (act && rank32 == 16) ? myMag : -1.f;
#pragma unroll
            for (int off = 1; off <= 32; off <<= 1) {
                a2 = fmaxf(a2, __shfl_xor(a2, off));
                b2 = fmaxf(b2, __shfl_xor(b2, off));
            }
            if (lane == 0) needref = (a2 - b2 < a2 * 1e-4f) ? 1 : 0;
        }
        __syncthreads();   // S6

        // ---- RARE: fp64 refinement (rotation recurrence; twiddles via sincos) ----
        if (needref) {
            for (int c = w; c < M; c += 4) {
                int k = candk[c];
                double ss, cs;   // step e^{-2pi i k*64/1024} = e^{-2pi i (k&15)/16}
                sincos(-6.283185307179586476925286766559e0 *
                       (double)(k & 15) / 16.0, &ss, &cs);
                double s0, c0;   // start e^{-2pi i (k*lane mod 1024)/1024}
                sincos(-6.283185307179586476925286766559e0 *
                       (double)((k * lane) & (T_LEN - 1)) / 1024.0, &s0, &c0);
                double wr = c0, wi = s0, cr = 0.0, ci = 0.0;
#pragma unroll
                for (int i = 0; i < 16; i++) {
                    double xv = (double)xs[lane + (i << 6)];
                    cr = fma(xv, wr, cr);
                    ci = fma(xv, wi, ci);
                    double nr = fma(wr, cs, -wi * ss);
                    double ni = fma(wr, ss,  wi * cs);
                    wr = nr; wi = ni;
                }
#pragma unroll
                for (int off = 1; off <= 32; off <<= 1) {
                    cr += __shfl_xor(cr, off);
                    ci += __shfl_xor(ci, off);
                }
                if (lane == 0) candc[c] = make_double2(cr, ci);
            }
        }
        __syncthreads();   // S7

        // ---- final write (slot = rank; order irrelevant downstream) ----
        int s = (b << 9) + d0 + ser;     // series id
        if (tid < 64) {
            if (!needref) {
                const float sc = 1.0f / 512.0f;
                if (lane < M && rank32 < K_SEL)
                    sel[(size_t)s * K_SEL + rank32] =
                        make_float4((float)myK, myV.x * sc, myV.y * sc, 0.f);
            } else {
                double m = -1.0; int k = 1 << 20; double sre = 0.0, sim = 0.0;
                if (lane < M) {
                    double2 d2 = candc[lane]; k = candk[lane];
                    m = d2.x * d2.x + d2.y * d2.y;
                    sre = d2.x; sim = d2.y;
                }
                int rank = 0;
                for (int j = 0; j < M; j++) {
                    double om = __shfl(m, j);
                    int    ok = __shfl(k, j);
                    rank += (om > m || (om == m && ok < k)) ? 1 : 0;
                }
                if (lane < M && rank < K_SEL) {
                    const double sc = 2.0 / (double)T_LEN;
                    sel[(size_t)s * K_SEL + rank] =
                        make_float4((float)k, (float)(sre * sc), (float)(sim * sc), 0.f);
                }
            }
        }
        // re-zero for next pass (visibility covered by next phase A->B barrier)
        hist[tid] = 0; hist[tid + 256] = 0;
        if (tid == 0) ncnt = 0;
        __syncthreads();
    }
}

// ---------------- kernel 2: sparse inverse reconstruction ----------------
__global__ __launch_bounds__(256) void k_recon(const float4* __restrict__ sel,
                                               float* __restrict__ out) {
    int blk = blockIdx.x;            // b(16) * dblk(8) * tchunk(8) = 1024
    int b    = blk >> 6;
    int dblk = (blk >> 3) & 7;
    int tc   = blk & 7;
    int tid  = threadIdx.x;
    int dd   = tid & 63;             // d within 64-wide tile
    int tg   = tid >> 6;             // 0..3 time-phase

    __shared__ float4 ssel[64][17];  // padded
    __shared__ float2 vt[T_LEN];     // V^m = e^{+2pi i m/1024}

#pragma unroll
    for (int i = 0; i < 4; i++) {
        int m = tid + 256 * i;
        float a = (6.2831853071795864769e0f / 1024.0f) * (float)m;
        vt[m] = make_float2(__cosf(a), __sinf(a));
    }
    int d0 = dblk * 64;
#pragma unroll
    for (int i = 0; i < 4; i++) {
        int l = tid + 256 * i;       // 1024 entries = 64 series * 16
        int sdd = l >> 4, j = l & 15;
        ssel[sdd][j] = sel[((size_t)(b * D_DIM + d0 + sdd)) * K_SEL + j];
    }
    __syncthreads();

    int tstart = tc * 128 + tg;
    float zr[16], zi[16], sr[16], si[16];
#pragma unroll
    for (int j = 0; j < 16; j++) {
        float4 e = ssel[dd][j];
        int k = (int)e.x;
        float2 v0 = vt[(k * tstart) & (T_LEN - 1)];
        zr[j] = e.y * v0.x - e.z * v0.y;   // z = c * V^{k*tstart}
        zi[j] = e.y * v0.y + e.z * v0.x;
        float2 st = vt[(k * 4) & (T_LEN - 1)];
        sr[j] = st.x; si[j] = st.y;        // step V^{4k}
    }

    float* ob = out + (size_t)b * OUT_T * D_DIM + (d0 + dd);
    for (int it = 0; it < 32; it++) {
        int t = tstart + it * 4;
        float v = 0.0f;
#pragma unroll
        for (int j = 0; j < 16; j++) {
            v += zr[j];
            float nr = zr[j] * sr[j] - zi[j] * si[j];
            float ni = zr[j] * si[j] + zi[j] * sr[j];
            zr[j] = nr; zi[j] = ni;
        }
        ob[(size_t)t * D_DIM] = v;
        if (t < OUT_T - T_LEN)               // replicate t+1024 (periodicity)
            ob[(size_t)(t + T_LEN) * D_DIM] = v;
    }
}

// ---------------- launch ----------------
extern "C" void kernel_launch(void* const* d_in, const int* in_sizes, int n_in,
                              void* d_out, int out_size, void* d_ws, size_t ws_size,
                              hipStream_t stream) {
    (void)in_sizes; (void)n_in; (void)out_size; (void)ws_size;
    const float* x = (const float*)d_in[0];
    float* out = (float*)d_out;
    float4* sel = (float4*)d_ws;

    hipLaunchKernelGGL(k_dft_topk, dim3(1024), dim3(256), 0, stream, x, sel);
    hipLaunchKernelGGL(k_recon,    dim3(1024), dim3(256), 0, stream, sel, out);
}

// Round 12
// 337.385 us; speedup vs baseline: 1.2422x; 1.2422x over previous
//
#include <hip/hip_runtime.h>
#include <math.h>

#define T_LEN   1024
#define D_DIM   512
#define B_DIM   16
#define OUT_T   1280
#define K_SEL   16
#define TSEL    17        /* candidate rank target: 16 + 1 safety */
#define MAXC    64
#define NSPB    8         /* series per block in k_dft_topk */

// d_ws layout:
//   [0, 16384)     double2 twd[1024]  e^{-2pi i m/1024} fp64  (refine only)
//   [16384, +2MiB) float4  sel[8192][16]  (k, re*2/N, im*2/N, 0)

// ---------------- kernel 0: fp64 twiddle table (refine path only) ----------------
__global__ void k_tables(double2* __restrict__ twd) {
    int m = blockIdx.x * blockDim.x + threadIdx.x;
    if (m >= T_LEN) return;
    const double w0 = 6.283185307179586476925286766559e0 / (double)T_LEN;
    double s, c;
    sincos(w0 * (double)m, &s, &c);
    twd[m] = make_double2(c, -s);    // e^{-i theta}
}

// ------- kernel 1: direct-staged fp32 CT DFT + 2-level histogram cut +
//         conditional fp64 refine (TABLE twiddles — no f64 sincos here).
//         One block = 8 series (b, d0..d0+7). -------
__global__ __launch_bounds__(256, 2) void k_dft_topk(const float* __restrict__ x,
                                                     const double2* __restrict__ twd,
                                                     float4* __restrict__ sel) {
    // XCD-pairing swizzle (bijective, 1024 = 8*128): hw ids j and j+8 sit on
    // the same XCD L2; map them to logical 2q,2q+1 so the 64B lines split at
    // the d0 boundary are fetched once per XCD.
    int blk  = ((blockIdx.x & 7) << 7) + (blockIdx.x >> 3);
    int b    = blk >> 6;
    int d0   = (blk & 63) * NSPB;
    int tid  = threadIdx.x;
    int lane = tid & 63;
    int w    = tid >> 6;             // wave id 0..3

    __shared__ float   xs2[NSPB][1032];           // 33 KB (pad 1032: 2-way stores)
    __shared__ __align__(16) char smemA[8448];    // zs (phase A/B) -> fineh (select)
    __shared__ float2  w32s[32];                  // e^{-2pi i m/32}
    __shared__ int     hist[512];                 // coarse histogram
    __shared__ int     candk[MAXC];
    __shared__ float2  candv[MAXC];               // fp32 (cr,ci) at gather
    __shared__ double2 candc[MAXC];               // fp64 refined (rare path)
    __shared__ int     Bsh, abovesh, fcsh, ncnt, needref;

    float2* zs    = (float2*)smemA;   // [32][33] z[k1][t0] padded
    int*    fineh = (int*)smemA;      // [1024]   fine histogram (after phase B)

    // ---- stage 8 series: x[b, t, d0+dd] -> xs2[dd][t] (float4, line-covered) ----
    const float* xb = x + ((size_t)b << 19) + d0;
#pragma unroll
    for (int i = 0; i < 8; i++) {
        int idx4 = tid + 256 * i;    // 0..2047
        int t = idx4 >> 1, q = idx4 & 1;
        float4 v = *(const float4*)(xb + ((size_t)t << 9) + 4 * q);
        xs2[4 * q + 0][t] = v.x; xs2[4 * q + 1][t] = v.y;
        xs2[4 * q + 2][t] = v.z; xs2[4 * q + 3][t] = v.w;
    }
    if (tid < 32) {                  // w32s[m] = e^{-2pi i m/32}
        float a = (-6.2831853071795864769e0f / 32.0f) * (float)tid;
        w32s[tid] = make_float2(__cosf(a), __sinf(a));
    }
    if (tid == 0) ncnt = 0;
    hist[tid] = 0; hist[tid + 256] = 0;
    __syncthreads();

    const float TH = -6.2831853071795864769e0f / 1024.0f;   // -2pi/1024

    for (int ser = 0; ser < NSPB; ser++) {
        const float* xs = xs2[ser];

        // ---- phase A: y[k1][t0] = sum_t1 x[32 t1+t0] W32^{k1 t1}; z = y*W1024^{k1 t0}
        {
            int k1  = tid & 31;
            int t0b = (tid >> 5) << 2;
            float yr0=0,yi0=0,yr1=0,yi1=0,yr2=0,yi2=0,yr3=0,yi3=0;
#pragma unroll
            for (int t1 = 0; t1 < 32; t1++) {
                const float4 xq = *(const float4*)&xs[32 * t1 + t0b];
                float2 wv = w32s[(k1 * t1) & 31];
                yr0 += xq.x * wv.x; yi0 += xq.x * wv.y;
                yr1 += xq.y * wv.x; yi1 += xq.y * wv.y;
                yr2 += xq.z * wv.x; yi2 += xq.z * wv.y;
                yr3 += xq.w * wv.x; yi3 += xq.w * wv.y;
            }
            float yrA[4] = {yr0, yr1, yr2, yr3};
            float yiA[4] = {yi0, yi1, yi2, yi3};
#pragma unroll
            for (int i = 0; i < 4; i++) {
                int t0 = t0b + i;
                int m  = (k1 * t0) & (T_LEN - 1);
                float a = TH * (float)m;           // tw = (cos, -sin) = (cn, sn)
                float sn = __sinf(a), cn = __cosf(a);
                zs[k1 * 33 + t0] = make_float2(yrA[i] * cn - yiA[i] * sn,
                                               yrA[i] * sn + yiA[i] * cn);
            }
        }
        __syncthreads();

        // ---- phase B (merged k/k+256: same zs row): c_k = sum_t0 z W32^{k0 t0}
        float crr[2], cii[2];
        int   bb[2],  ff[2];
        {
            int kb1 = tid & 31;
            int k0a = tid >> 5;
            float cr0=0, ci0=0, cr1=0, ci1=0;
#pragma unroll
            for (int t0 = 0; t0 < 32; t0++) {
                float2 z  = zs[kb1 * 33 + t0];
                float2 wa = w32s[(k0a * t0) & 31];
                float2 wb = w32s[((k0a + 8) * t0) & 31];
                cr0 += z.x * wa.x - z.y * wa.y;
                ci0 += z.x * wa.y + z.y * wa.x;
                cr1 += z.x * wb.x - z.y * wb.y;
                ci1 += z.x * wb.y + z.y * wb.x;
            }
            crr[0] = cr0; cii[0] = ci0; crr[1] = cr1; cii[1] = ci1;
        }
#pragma unroll
        for (int kk = 0; kk < 2; kk++) {
            int k = tid + kk * 256;
            if (k == 0) { bb[kk] = -1; ff[kk] = 0; }
            else {
                float mag = crr[kk] * crr[kk] + cii[kk] * cii[kk];
                unsigned int bits = __float_as_uint(mag);
                bb[kk] = (int)(bits >> 22);            // monotone coarse bucket
                ff[kk] = (int)((bits >> 12) & 1023);   // monotone within coarse
                atomicAdd(&hist[bb[kk]], 1);
            }
        }
        __syncthreads();   // S1: hist done; zs dead -> fineh

        // ---- zero fine histogram (overlays zs) ----
#pragma unroll
        for (int i = 0; i < 4; i++) fineh[tid + 256 * i] = 0;

        // ---- wave 0: coarse suffix-scan; B = largest bucket with suffix >= TSEL
        if (tid < 64) {
            int c8[8]; int ssum = 0;
            int top = 511 - lane * 8;
#pragma unroll
            for (int j = 0; j < 8; j++) { c8[j] = hist[top - j]; ssum += c8[j]; }
            int inc = ssum;
#pragma unroll
            for (int off = 1; off < 64; off <<= 1) {
                int o = __shfl_up(inc, off);
                if (lane >= off) inc += o;
            }
            int P = inc - ssum;
            if (P < TSEL && P + ssum >= TSEL) {     // exactly one lane
                int run = P;
#pragma unroll
                for (int j = 0; j < 8; j++) {
                    run += c8[j];
                    if (run >= TSEL) { Bsh = top - j; abovesh = run - c8[j]; break; }
                }
            }
        }
        __syncthreads();   // S2

        // ---- fine histogram over bins in bucket B ----
        int Bcut = Bsh;
        if (bb[0] == Bcut) atomicAdd(&fineh[ff[0]], 1);
        if (bb[1] == Bcut) atomicAdd(&fineh[ff[1]], 1);
        __syncthreads();   // S3

        // ---- wave 0: fine suffix-scan; sub-cut; -1 sub-bucket margin ----
        if (tid < 64) {
            int f16[16]; int ssum = 0;
            int ftop = 1023 - lane * 16;
#pragma unroll
            for (int j = 0; j < 16; j++) { f16[j] = fineh[ftop - j]; ssum += f16[j]; }
            int inc = ssum;
#pragma unroll
            for (int off = 1; off < 64; off <<= 1) {
                int o = __shfl_up(inc, off);
                if (lane >= off) inc += o;
            }
            int P   = inc - ssum;
            int tgt = TSEL - abovesh;    // >= 1
            if (P < tgt && P + ssum >= tgt) {       // exactly one lane
                int run = P;
#pragma unroll
                for (int j = 0; j < 16; j++) {
                    run += f16[j];
                    if (run >= tgt) {
                        int fc = ftop - j;
                        fcsh = fc > 0 ? fc - 1 : 0;
                        break;
                    }
                }
            }
        }
        __syncthreads();   // S4

        // ---- gather candidates with values ----
        int fcm = fcsh;
        if (bb[0] > Bcut || (bb[0] == Bcut && ff[0] >= fcm)) {
            int sl = atomicAdd(&ncnt, 1);
            if (sl < MAXC) { candk[sl] = tid; candv[sl] = make_float2(crr[0], cii[0]); }
        }
        if (bb[1] > Bcut || (bb[1] == Bcut && ff[1] >= fcm)) {
            int sl = atomicAdd(&ncnt, 1);
            if (sl < MAXC) { candk[sl] = tid + 256; candv[sl] = make_float2(crr[1], cii[1]); }
        }
        __syncthreads();   // S5
        int M = ncnt < MAXC ? ncnt : MAXC;

        // ---- wave 0: fp32 rank-count + boundary-gap test ----
        int    rank32 = 64;
        float  myMag  = -1.f; int myK = 1 << 20; float2 myV = make_float2(0.f, 0.f);
        if (tid < 64) {
            bool act = lane < M;
            if (act) {
                myK = candk[lane]; myV = candv[lane];
                myMag = myV.x * myV.x + myV.y * myV.y;
            }
            rank32 = 0;
            for (int j = 0; j < M; j++) {
                float om = __shfl(myMag, j);
                int   ok = __shfl(myK, j);
                rank32 += (om > myMag || (om == myMag && ok < myK)) ? 1 : 0;
            }
            float a2 = (act && rank32 == 15) ? myMag : -1.f;
            float b2 = (act && rank32 == 16) ? myMag : -1.f;
#pragma unroll
            for (int off = 1; off <= 32; off <<= 1) {
                a2 = fmaxf(a2, __shfl_xor(a2, off));
                b2 = fmaxf(b2, __shfl_xor(b2, off));
            }
            if (lane == 0) needref = (a2 - b2 < a2 * 1e-4f) ? 1 : 0;
        }
        __syncthreads();   // S6

        // ---- RARE: fp64 refinement (rotation recurrence; TABLE twiddles) ----
        if (needref) {
            for (int c = w; c < M; c += 4) {
                int k = candk[c];
                double2 st = twd[(k << 6) & (T_LEN - 1)];   // step e^{-2pi i 64k/1024}
                double2 w0 = twd[(k * lane) & (T_LEN - 1)]; // start
                double wr = w0.x, wi = w0.y, cr = 0.0, ci = 0.0;
#pragma unroll
                for (int i = 0; i < 16; i++) {
                    double xv = (double)xs[lane + (i << 6)];
                    cr = fma(xv, wr, cr);
                    ci = fma(xv, wi, ci);
                    double nr = fma(wr, st.x, -wi * st.y);
                    double ni = fma(wr, st.y,  wi * st.x);
                    wr = nr; wi = ni;
                }
#pragma unroll
                for (int off = 1; off <= 32; off <<= 1) {
                    cr += __shfl_xor(cr, off);
                    ci += __shfl_xor(ci, off);
                }
                if (lane == 0) candc[c] = make_double2(cr, ci);
            }
        }
        __syncthreads();   // S7

        // ---- final write (slot = rank; order irrelevant downstream) ----
        int s = (b << 9) + d0 + ser;     // series id
        if (tid < 64) {
            if (!needref) {
                const float sc = 1.0f / 512.0f;
                if (lane < M && rank32 < K_SEL)
                    sel[(size_t)s * K_SEL + rank32] =
                        make_float4((float)myK, myV.x * sc, myV.y * sc, 0.f);
            } else {
                double m = -1.0; int k = 1 << 20; double sre = 0.0, sim = 0.0;
                if (lane < M) {
                    double2 d2 = candc[lane]; k = candk[lane];
                    m = d2.x * d2.x + d2.y * d2.y;
                    sre = d2.x; sim = d2.y;
                }
                int rank = 0;
                for (int j = 0; j < M; j++) {
                    double om = __shfl(m, j);
                    int    ok = __shfl(k, j);
                    rank += (om > m || (om == m && ok < k)) ? 1 : 0;
                }
                if (lane < M && rank < K_SEL) {
                    const double sc = 2.0 / (double)T_LEN;
                    sel[(size_t)s * K_SEL + rank] =
                        make_float4((float)k, (float)(sre * sc), (float)(sim * sc), 0.f);
                }
            }
        }
        // re-zero for next pass (visibility covered by next phase A->B barrier)
        hist[tid] = 0; hist[tid + 256] = 0;
        if (tid == 0) ncnt = 0;
        __syncthreads();
    }
}

// ---------------- kernel 2: sparse inverse reconstruction ----------------
__global__ __launch_bounds__(256) void k_recon(const float4* __restrict__ sel,
                                               float* __restrict__ out) {
    int blk = blockIdx.x;            // b(16) * dblk(8) * tchunk(8) = 1024
    int b    = blk >> 6;
    int dblk = (blk >> 3) & 7;
    int tc   = blk & 7;
    int tid  = threadIdx.x;
    int dd   = tid & 63;             // d within 64-wide tile
    int tg   = tid >> 6;             // 0..3 time-phase

    __shared__ float4 ssel[64][17];  // padded
    __shared__ float2 vt[T_LEN];     // V^m = e^{+2pi i m/1024}

#pragma unroll
    for (int i = 0; i < 4; i++) {
        int m = tid + 256 * i;
        float a = (6.2831853071795864769e0f / 1024.0f) * (float)m;
        vt[m] = make_float2(__cosf(a), __sinf(a));
    }
    int d0 = dblk * 64;
#pragma unroll
    for (int i = 0; i < 4; i++) {
        int l = tid + 256 * i;       // 1024 entries = 64 series * 16
        int sdd = l >> 4, j = l & 15;
        ssel[sdd][j] = sel[((size_t)(b * D_DIM + d0 + sdd)) * K_SEL + j];
    }
    __syncthreads();

    int tstart = tc * 128 + tg;
    float zr[16], zi[16], sr[16], si[16];
#pragma unroll
    for (int j = 0; j < 16; j++) {
        float4 e = ssel[dd][j];
        int k = (int)e.x;
        float2 v0 = vt[(k * tstart) & (T_LEN - 1)];
        zr[j] = e.y * v0.x - e.z * v0.y;   // z = c * V^{k*tstart}
        zi[j] = e.y * v0.y + e.z * v0.x;
        float2 st = vt[(k * 4) & (T_LEN - 1)];
        sr[j] = st.x; si[j] = st.y;        // step V^{4k}
    }

    float* ob = out + (size_t)b * OUT_T * D_DIM + (d0 + dd);
    for (int it = 0; it < 32; it++) {
        int t = tstart + it * 4;
        float v = 0.0f;
#pragma unroll
        for (int j = 0; j < 16; j++) {
            v += zr[j];
            float nr = zr[j] * sr[j] - zi[j] * si[j];
            float ni = zr[j] * si[j] + zi[j] * sr[j];
            zr[j] = nr; zi[j] = ni;
        }
        ob[(size_t)t * D_DIM] = v;
        if (t < OUT_T - T_LEN)               // replicate t+1024 (periodicity)
            ob[(size_t)(t + T_LEN) * D_DIM] = v;
    }
}

// ---------------- launch ----------------
extern "C" void kernel_launch(void* const* d_in, const int* in_sizes, int n_in,
                              void* d_out, int out_size, void* d_ws, size_t ws_size,
                              hipStream_t stream) {
    (void)in_sizes; (void)n_in; (void)out_size; (void)ws_size;
    const float* x = (const float*)d_in[0];
    float* out = (float*)d_out;
    char* ws = (char*)d_ws;

    double2* twd = (double2*)ws;
    float4*  sel = (float4*)(ws + 16384);

    hipLaunchKernelGGL(k_tables,   dim3(4),    dim3(256), 0, stream, twd);
    hipLaunchKernelGGL(k_dft_topk, dim3(1024), dim3(256), 0, stream, x, twd, sel);
    hipLaunchKernelGGL(k_recon,    dim3(1024), dim3(256), 0, stream, sel, out);
}